// Round 2
// baseline (2964.206 us; speedup 1.0000x reference)
//
#include <hip/hip_runtime.h>

#define D 128
typedef long long i64;

__device__ inline float4 fma4(float a, float4 b, float4 c) {
  c.x = fmaf(a, b.x, c.x);
  c.y = fmaf(a, b.y, c.y);
  c.z = fmaf(a, b.z, c.z);
  c.w = fmaf(a, b.w, c.w);
  return c;
}

// Detect whether edge_index is int64 (odd u32 words all zero) or int32.
// Writes flag=1 for int64, 0 for int32. All on-device: graph-capture safe.
__global__ void k_detect(const unsigned* __restrict__ w, int* __restrict__ flag) {
  __shared__ unsigned red[256];
  unsigned v = 0;
  for (int i = threadIdx.x; i < 2048; i += 256) v |= w[2 * i + 1];
  red[threadIdx.x] = v;
  __syncthreads();
  for (int s = 128; s > 0; s >>= 1) {
    if ((int)threadIdx.x < s) red[threadIdx.x] |= red[threadIdx.x + s];
    __syncthreads();
  }
  if (threadIdx.x == 0) *flag = (red[0] == 0u) ? 1 : 0;
}

// deg starts at 1.0 (self-loop); also zero BN accumulators.
__global__ void k_init(float* __restrict__ deg, float* __restrict__ colsum,
                       float* __restrict__ colsumsq, int n) {
  int i = blockIdx.x * blockDim.x + threadIdx.x;
  if (i < n) deg[i] = 1.0f;
  if (i < D) { colsum[i] = 0.f; colsumsq[i] = 0.f; }
}

__global__ void k_deg(const int* __restrict__ ei32, const i64* __restrict__ ei64,
                      const int* __restrict__ flag, int e, float* deg) {
  int is64 = *flag;
  for (long long i = (long long)blockIdx.x * blockDim.x + threadIdx.x; i < e;
       i += (long long)gridDim.x * blockDim.x) {
    long long d = is64 ? ei64[e + i] : (long long)ei32[e + i];
    atomicAdd(&deg[d], 1.0f);
  }
}

__global__ void k_rsqrt(float* deg, int n) {
  int i = blockIdx.x * blockDim.x + threadIdx.x;
  if (i < n) deg[i] = rsqrtf(deg[i]);
}

// Y[n x 128] = X[n x 128] @ W[128 x 128], f32 (no fp32 MFMA on CDNA4).
// W staged in LDS (64KB); 16 rows of X staged per iter; each thread: 2 rows x 4 cols.
__global__ __launch_bounds__(256) void k_gemm(const float* __restrict__ X,
                                              const float* __restrict__ W,
                                              float* __restrict__ Y, int n) {
  __shared__ float Wl[128 * 128];
  __shared__ float Xl[16][128];
  int t = threadIdx.x;
  for (int i = t; i < 128 * 32; i += 256)
    ((float4*)Wl)[i] = ((const float4*)W)[i];
  int r0 = t >> 5;            // 0..7
  int c4 = (t & 31) << 2;     // column base
  for (int row0 = blockIdx.x * 16; row0 < n; row0 += gridDim.x * 16) {
    __syncthreads();          // protects W (first iter) and Xl reuse
    int nrows = min(16, n - row0);
    for (int i = t; i < nrows * 32; i += 256)
      ((float4*)Xl)[i] = ((const float4*)(X + (size_t)row0 * D))[i];
    __syncthreads();
    float4 acc0 = {0.f, 0.f, 0.f, 0.f};
    float4 acc1 = {0.f, 0.f, 0.f, 0.f};
#pragma unroll 8
    for (int k = 0; k < 128; ++k) {
      float4 wv = *(const float4*)&Wl[k * 128 + c4];
      float x0 = Xl[r0][k];
      float x1 = Xl[r0 + 8][k];
      acc0 = fma4(x0, wv, acc0);
      acc1 = fma4(x1, wv, acc1);
    }
    if (row0 + r0 < n) *(float4*)&Y[(size_t)(row0 + r0) * D + c4] = acc0;
    if (row0 + r0 + 8 < n) *(float4*)&Y[(size_t)(row0 + r0 + 8) * D + c4] = acc1;
  }
}

// agg[i][:] = hw[i][:] * dis[i]^2 + b[:]   (self-loop contribution + bias)
__global__ void k_selfinit(const float* __restrict__ hw, const float* __restrict__ dis,
                           const float* __restrict__ b, float* __restrict__ agg, int n) {
  size_t i = (size_t)blockIdx.x * blockDim.x + threadIdx.x;
  if (i >= (size_t)n * 32) return;
  size_t row = i >> 5;
  int c = (int)(i & 31);
  float w = dis[row]; w *= w;
  float4 v = ((const float4*)hw)[i];
  float4 bv = ((const float4*)b)[c];
  v.x = fmaf(v.x, w, bv.x); v.y = fmaf(v.y, w, bv.y);
  v.z = fmaf(v.z, w, bv.z); v.w = fmaf(v.w, w, bv.w);
  ((float4*)agg)[i] = v;
}

// out[i][:] = h1[i][:] + hw2[i][:] * dis[i]^2 + b2[:]
__global__ void k_selfinit2(const float* __restrict__ h1, const float* __restrict__ hw2,
                            const float* __restrict__ dis, const float* __restrict__ b,
                            float* __restrict__ out, int n) {
  size_t i = (size_t)blockIdx.x * blockDim.x + threadIdx.x;
  if (i >= (size_t)n * 32) return;
  size_t row = i >> 5;
  int c = (int)(i & 31);
  float w = dis[row]; w *= w;
  float4 v = ((const float4*)hw2)[i];
  float4 h = ((const float4*)h1)[i];
  float4 bv = ((const float4*)b)[c];
  v.x = fmaf(v.x, w, bv.x) + h.x; v.y = fmaf(v.y, w, bv.y) + h.y;
  v.z = fmaf(v.z, w, bv.z) + h.z; v.w = fmaf(v.w, w, bv.w) + h.w;
  ((float4*)out)[i] = v;
}

// For each edge e, 32 threads: dst_feat[dst] += src_feat[src] * dis[src]*dis[dst]
__global__ __launch_bounds__(256) void k_scatter(const int* __restrict__ ei32,
                                                 const i64* __restrict__ ei64,
                                                 const int* __restrict__ flag, int e,
                                                 const float* __restrict__ dis,
                                                 const float* __restrict__ src_feat,
                                                 float* dst_feat) {
  int is64 = *flag;
  size_t total = (size_t)e * 32;
  for (size_t gid = (size_t)blockIdx.x * blockDim.x + threadIdx.x; gid < total;
       gid += (size_t)gridDim.x * blockDim.x) {
    size_t eidx = gid >> 5;
    int t = (int)(gid & 31);
    long long s, dv;
    if (is64) { s = ei64[eidx]; dv = ei64[e + eidx]; }
    else      { s = ei32[eidx]; dv = ei32[e + eidx]; }
    float w = dis[s] * dis[dv];
    float4 v = ((const float4*)src_feat)[(size_t)s * 32 + t];
    float* dp = dst_feat + (size_t)dv * D + t * 4;
    atomicAdd(dp + 0, v.x * w);
    atomicAdd(dp + 1, v.y * w);
    atomicAdd(dp + 2, v.z * w);
    atomicAdd(dp + 3, v.w * w);
  }
}

// Column sums / sum-of-squares for BN (biased var). 2 rows per block-iter.
__global__ __launch_bounds__(256) void k_bnstats(const float* __restrict__ h, int n,
                                                 float* colsum, float* colsumsq) {
  int t = threadIdx.x;
  int col = t & 127;
  int rh = t >> 7;  // 0 or 1
  float s = 0.f, s2 = 0.f;
  for (int r = blockIdx.x * 2 + rh; r < n; r += gridDim.x * 2) {
    float v = h[(size_t)r * D + col];
    s += v;
    s2 += v * v;
  }
  atomicAdd(&colsum[col], s);
  atomicAdd(&colsumsq[col], s2);
}

__global__ void k_bnfinish(const float* __restrict__ colsum, const float* __restrict__ colsumsq,
                           const float* __restrict__ gamma, const float* __restrict__ beta,
                           float* __restrict__ scale, float* __restrict__ shift, int n) {
  int d = threadIdx.x;
  float inv_n = 1.0f / (float)n;
  float mu = colsum[d] * inv_n;
  float var = colsumsq[d] * inv_n - mu * mu;
  float sc = gamma[d] * rsqrtf(var + 1e-5f);
  scale[d] = sc;
  shift[d] = beta[d] - mu * sc;
}

// h1 = relu(hpre * scale + shift)
__global__ void k_bnapply(const float* __restrict__ hpre, const float* __restrict__ scale,
                          const float* __restrict__ shift, float* __restrict__ h1, int n) {
  size_t i = (size_t)blockIdx.x * blockDim.x + threadIdx.x;
  if (i >= (size_t)n * 32) return;
  int c = (int)(i & 31);
  float4 v = ((const float4*)hpre)[i];
  float4 sc = ((const float4*)scale)[c];
  float4 sh = ((const float4*)shift)[c];
  v.x = fmaxf(fmaf(v.x, sc.x, sh.x), 0.f);
  v.y = fmaxf(fmaf(v.y, sc.y, sh.y), 0.f);
  v.z = fmaxf(fmaf(v.z, sc.z, sh.z), 0.f);
  v.w = fmaxf(fmaf(v.w, sc.w, sh.w), 0.f);
  ((float4*)h1)[i] = v;
}

extern "C" void kernel_launch(void* const* d_in, const int* in_sizes, int n_in,
                              void* d_out, int out_size, void* d_ws, size_t ws_size,
                              hipStream_t stream) {
  const float* x     = (const float*)d_in[0];
  const int*   ei32  = (const int*)d_in[1];
  const i64*   ei64  = (const i64*)d_in[1];
  const float* W1    = (const float*)d_in[2];
  const float* b1    = (const float*)d_in[3];
  const float* W2    = (const float*)d_in[4];
  const float* b2    = (const float*)d_in[5];
  const float* gamma = (const float*)d_in[6];
  const float* beta  = (const float*)d_in[7];
  float* out = (float*)d_out;

  const int n = in_sizes[0] / D;  // 50000
  const int e = in_sizes[1] / 2;  // 800000

  // Workspace layout (all f32), ~51.5 MB total
  float* dis      = (float*)d_ws;                       // n (deg -> rsqrt(deg))
  float* bufA     = dis + (((size_t)n + 255) & ~255ULL); // n*D: hw1, then h1
  float* bufB     = bufA + (size_t)n * D;                // n*D: h1_pre, then hw2
  float* colsum   = bufB + (size_t)n * D;                // D
  float* colsumsq = colsum + D;                          // D
  float* scale    = colsumsq + D;                        // D
  float* shift    = scale + D;                           // D
  int*   flag     = (int*)(shift + D);                   // 1

  int nb256 = (n + 255) / 256;
  int fb256 = (n * 32 + 255) / 256;
  int sb    = (int)(((size_t)e * 32 + 255) / 256);

  k_detect<<<1, 256, 0, stream>>>((const unsigned*)d_in[1], flag);
  k_init<<<nb256, 256, 0, stream>>>(dis, colsum, colsumsq, n);
  k_deg<<<(e + 255) / 256, 256, 0, stream>>>(ei32, ei64, flag, e, dis);
  k_rsqrt<<<nb256, 256, 0, stream>>>(dis, n);

  // layer 1
  k_gemm<<<512, 256, 0, stream>>>(x, W1, bufA, n);
  k_selfinit<<<fb256, 256, 0, stream>>>(bufA, dis, b1, bufB, n);
  k_scatter<<<sb, 256, 0, stream>>>(ei32, ei64, flag, e, dis, bufA, bufB);
  k_bnstats<<<1024, 256, 0, stream>>>(bufB, n, colsum, colsumsq);
  k_bnfinish<<<1, D, 0, stream>>>(colsum, colsumsq, gamma, beta, scale, shift, n);
  k_bnapply<<<fb256, 256, 0, stream>>>(bufB, scale, shift, bufA, n);

  // layer 2 + skip
  k_gemm<<<512, 256, 0, stream>>>(bufA, W2, bufB, n);
  k_selfinit2<<<fb256, 256, 0, stream>>>(bufA, bufB, dis, b2, out, n);
  k_scatter<<<sb, 256, 0, stream>>>(ei32, ei64, flag, e, dis, bufB, out);
}

// Round 3
// 527.746 us; speedup vs baseline: 5.6167x; 5.6167x over previous
//
#include <hip/hip_runtime.h>

#define D 128
typedef long long i64;

__device__ inline float4 fma4(float a, float4 b, float4 c) {
  c.x = fmaf(a, b.x, c.x);
  c.y = fmaf(a, b.y, c.y);
  c.z = fmaf(a, b.z, c.z);
  c.w = fmaf(a, b.w, c.w);
  return c;
}

// Detect whether edge_index is int64 (odd u32 words all zero) or int32.
__global__ void k_detect(const unsigned* __restrict__ w, int* __restrict__ flag) {
  __shared__ unsigned red[256];
  unsigned v = 0;
  for (int i = threadIdx.x; i < 2048; i += 256) v |= w[2 * i + 1];
  red[threadIdx.x] = v;
  __syncthreads();
  for (int s = 128; s > 0; s >>= 1) {
    if ((int)threadIdx.x < s) red[threadIdx.x] |= red[threadIdx.x + s];
    __syncthreads();
  }
  if (threadIdx.x == 0) *flag = (red[0] == 0u) ? 1 : 0;
}

// Zero cnt + BN accumulators.
__global__ void k_init(int* __restrict__ cnt, float* __restrict__ colsum,
                       float* __restrict__ colsumsq, int n) {
  int i = blockIdx.x * blockDim.x + threadIdx.x;
  if (i < n) cnt[i] = 0;
  if (i < D) { colsum[i] = 0.f; colsumsq[i] = 0.f; }
}

// Count incoming edges per dst (int atomics).
__global__ void k_count(const int* __restrict__ ei32, const i64* __restrict__ ei64,
                        const int* __restrict__ flag, int e, int* __restrict__ cnt) {
  int is64 = *flag;
  for (long long i = (long long)blockIdx.x * blockDim.x + threadIdx.x; i < e;
       i += (long long)gridDim.x * blockDim.x) {
    int d = is64 ? (int)ei64[e + i] : ei32[e + i];
    atomicAdd(&cnt[d], 1);
  }
}

// Single-block exclusive scan of cnt -> rowptr (row starts); also dis = rsqrt(cnt+1).
__global__ __launch_bounds__(1024) void k_scan(const int* __restrict__ cnt,
                                               int* __restrict__ rowptr,
                                               float* __restrict__ dis, int n) {
  __shared__ int sdata[1024];
  __shared__ int carry_s;
  int t = threadIdx.x;
  if (t == 0) carry_s = 0;
  __syncthreads();
  for (int base = 0; base < n; base += 1024) {
    int i = base + t;
    int c = (i < n) ? cnt[i] : 0;
    sdata[t] = c;
    __syncthreads();
    for (int off = 1; off < 1024; off <<= 1) {
      int v = (t >= off) ? sdata[t - off] : 0;
      __syncthreads();
      sdata[t] += v;
      __syncthreads();
    }
    int incl = sdata[t];
    int excl = incl - c;
    if (i < n) {
      rowptr[i] = carry_s + excl;
      dis[i] = rsqrtf((float)(c + 1));
    }
    __syncthreads();
    if (t == 1023) carry_s += incl;
    __syncthreads();
  }
}

// Counting-sort fill: slot = rowptr[dst]++ (atomic). Afterwards rowptr[r] == row end.
__global__ void k_fill(const int* __restrict__ ei32, const i64* __restrict__ ei64,
                       const int* __restrict__ flag, int e,
                       int* __restrict__ rowptr, int* __restrict__ csr_src) {
  int is64 = *flag;
  for (long long i = (long long)blockIdx.x * blockDim.x + threadIdx.x; i < e;
       i += (long long)gridDim.x * blockDim.x) {
    int s, d;
    if (is64) { s = (int)ei64[i]; d = (int)ei64[e + i]; }
    else      { s = ei32[i];      d = ei32[e + i]; }
    int slot = atomicAdd(&rowptr[d], 1);
    csr_src[slot] = s;
  }
}

// Y[n x 128] = X[n x 128] @ W[128 x 128], f32 vector ALU (no fp32 MFMA on CDNA4).
__global__ __launch_bounds__(256) void k_gemm(const float* __restrict__ X,
                                              const float* __restrict__ W,
                                              float* __restrict__ Y, int n) {
  __shared__ float Wl[128 * 128];
  __shared__ float Xl[16][128];
  int t = threadIdx.x;
  for (int i = t; i < 128 * 32; i += 256)
    ((float4*)Wl)[i] = ((const float4*)W)[i];
  int r0 = t >> 5;
  int c4 = (t & 31) << 2;
  for (int row0 = blockIdx.x * 16; row0 < n; row0 += gridDim.x * 16) {
    __syncthreads();
    int nrows = min(16, n - row0);
    for (int i = t; i < nrows * 32; i += 256)
      ((float4*)Xl)[i] = ((const float4*)(X + (size_t)row0 * D))[i];
    __syncthreads();
    float4 acc0 = {0.f, 0.f, 0.f, 0.f};
    float4 acc1 = {0.f, 0.f, 0.f, 0.f};
#pragma unroll 8
    for (int k = 0; k < 128; ++k) {
      float4 wv = *(const float4*)&Wl[k * 128 + c4];
      float x0 = Xl[r0][k];
      float x1 = Xl[r0 + 8][k];
      acc0 = fma4(x0, wv, acc0);
      acc1 = fma4(x1, wv, acc1);
    }
    if (row0 + r0 < n) *(float4*)&Y[(size_t)(row0 + r0) * D + c4] = acc0;
    if (row0 + r0 + 8 < n) *(float4*)&Y[(size_t)(row0 + r0 + 8) * D + c4] = acc1;
  }
}

// Pull-gather: one 32-lane group per dst row.
// out[r] = bias + dis[r]^2*feat[r] (+ addf[r]) + sum_j dis[s_j]*dis[r]*feat[s_j]
template <bool ADD>
__global__ __launch_bounds__(256) void k_gather(const float* __restrict__ feat,
                                                const float* __restrict__ addf,
                                                const float* __restrict__ bias,
                                                const float* __restrict__ dis,
                                                const int* __restrict__ rowptr,
                                                const int* __restrict__ csr_src,
                                                float* __restrict__ out, int n) {
  int gid = blockIdx.x * blockDim.x + threadIdx.x;
  int group = gid >> 5;
  int lane = threadIdx.x & 31;
  int ngroups = (gridDim.x * blockDim.x) >> 5;
  for (int r = group; r < n; r += ngroups) {
    int start = (r == 0) ? 0 : rowptr[r - 1];  // rowptr holds row ENDS after k_fill
    int end = rowptr[r];
    float dr = dis[r];
    float4 acc = ((const float4*)bias)[lane];
    float4 sv = ((const float4*)(feat + (size_t)r * D))[lane];
    acc = fma4(dr * dr, sv, acc);
    if (ADD) {
      float4 h = ((const float4*)(addf + (size_t)r * D))[lane];
      acc.x += h.x; acc.y += h.y; acc.z += h.z; acc.w += h.w;
    }
    float4 acc1 = {0.f, 0.f, 0.f, 0.f};
    int j = start;
    for (; j + 2 <= end; j += 2) {
      int s0 = csr_src[j];
      int s1 = csr_src[j + 1];
      float w0 = dis[s0] * dr;
      float w1 = dis[s1] * dr;
      float4 v0 = ((const float4*)(feat + (size_t)s0 * D))[lane];
      float4 v1 = ((const float4*)(feat + (size_t)s1 * D))[lane];
      acc = fma4(w0, v0, acc);
      acc1 = fma4(w1, v1, acc1);
    }
    if (j < end) {
      int s0 = csr_src[j];
      float w0 = dis[s0] * dr;
      float4 v0 = ((const float4*)(feat + (size_t)s0 * D))[lane];
      acc = fma4(w0, v0, acc);
    }
    acc.x += acc1.x; acc.y += acc1.y; acc.z += acc1.z; acc.w += acc1.w;
    ((float4*)(out + (size_t)r * D))[lane] = acc;
  }
}

// Column sums / sum-of-squares for BN (biased var).
__global__ __launch_bounds__(256) void k_bnstats(const float* __restrict__ h, int n,
                                                 float* colsum, float* colsumsq) {
  int t = threadIdx.x;
  int col = t & 127;
  int rh = t >> 7;
  float s = 0.f, s2 = 0.f;
  for (int r = blockIdx.x * 2 + rh; r < n; r += gridDim.x * 2) {
    float v = h[(size_t)r * D + col];
    s += v;
    s2 += v * v;
  }
  atomicAdd(&colsum[col], s);
  atomicAdd(&colsumsq[col], s2);
}

__global__ void k_bnfinish(const float* __restrict__ colsum, const float* __restrict__ colsumsq,
                           const float* __restrict__ gamma, const float* __restrict__ beta,
                           float* __restrict__ scale, float* __restrict__ shift, int n) {
  int d = threadIdx.x;
  float inv_n = 1.0f / (float)n;
  float mu = colsum[d] * inv_n;
  float var = colsumsq[d] * inv_n - mu * mu;
  float sc = gamma[d] * rsqrtf(var + 1e-5f);
  scale[d] = sc;
  shift[d] = beta[d] - mu * sc;
}

// h1 = relu(hpre * scale + shift)
__global__ void k_bnapply(const float* __restrict__ hpre, const float* __restrict__ scale,
                          const float* __restrict__ shift, float* __restrict__ h1, int n) {
  size_t i = (size_t)blockIdx.x * blockDim.x + threadIdx.x;
  if (i >= (size_t)n * 32) return;
  int c = (int)(i & 31);
  float4 v = ((const float4*)hpre)[i];
  float4 sc = ((const float4*)scale)[c];
  float4 sh = ((const float4*)shift)[c];
  v.x = fmaxf(fmaf(v.x, sc.x, sh.x), 0.f);
  v.y = fmaxf(fmaf(v.y, sc.y, sh.y), 0.f);
  v.z = fmaxf(fmaf(v.z, sc.z, sh.z), 0.f);
  v.w = fmaxf(fmaf(v.w, sc.w, sh.w), 0.f);
  ((float4*)h1)[i] = v;
}

extern "C" void kernel_launch(void* const* d_in, const int* in_sizes, int n_in,
                              void* d_out, int out_size, void* d_ws, size_t ws_size,
                              hipStream_t stream) {
  const float* x     = (const float*)d_in[0];
  const int*   ei32  = (const int*)d_in[1];
  const i64*   ei64  = (const i64*)d_in[1];
  const float* W1    = (const float*)d_in[2];
  const float* b1    = (const float*)d_in[3];
  const float* W2    = (const float*)d_in[4];
  const float* b2    = (const float*)d_in[5];
  const float* gamma = (const float*)d_in[6];
  const float* beta  = (const float*)d_in[7];
  float* out = (float*)d_out;

  const int n = in_sizes[0] / D;  // 50000
  const int e = in_sizes[1] / 2;  // 800000

  // Workspace layout (~55 MB):
  size_t npad = ((size_t)n + 255) & ~255ULL;
  size_t epad = ((size_t)e + 255) & ~255ULL;
  float* dis     = (float*)d_ws;            // n
  int*   cnt     = (int*)(dis + npad);      // n
  int*   rowptr  = cnt + npad;              // n (starts -> ends after fill)
  int*   csr_src = rowptr + npad;           // e
  float* bufA    = (float*)(csr_src + epad);// n*D
  float* bufB    = bufA + (size_t)n * D;    // n*D
  float* colsum   = bufB + (size_t)n * D;   // D
  float* colsumsq = colsum + D;             // D
  float* scale    = colsumsq + D;           // D
  float* shift    = scale + D;              // D
  int*   flag     = (int*)(shift + D);      // 1

  int nb256 = (n + 255) / 256;
  int fb256 = (n * 32 + 255) / 256;
  int eb256 = (e + 255) / 256;
  int gb    = (n + 7) / 8;  // gather: 8 rows per 256-thread block

  // CSR build (shared by both layers)
  k_detect<<<1, 256, 0, stream>>>((const unsigned*)d_in[1], flag);
  k_init<<<nb256, 256, 0, stream>>>(cnt, colsum, colsumsq, n);
  k_count<<<eb256, 256, 0, stream>>>(ei32, ei64, flag, e, cnt);
  k_scan<<<1, 1024, 0, stream>>>(cnt, rowptr, dis, n);
  k_fill<<<eb256, 256, 0, stream>>>(ei32, ei64, flag, e, rowptr, csr_src);

  // layer 1: conv -> BN -> relu
  k_gemm<<<512, 256, 0, stream>>>(x, W1, bufA, n);
  k_gather<false><<<gb, 256, 0, stream>>>(bufA, nullptr, b1, dis, rowptr, csr_src, bufB, n);
  k_bnstats<<<1024, 256, 0, stream>>>(bufB, n, colsum, colsumsq);
  k_bnfinish<<<1, D, 0, stream>>>(colsum, colsumsq, gamma, beta, scale, shift, n);
  k_bnapply<<<fb256, 256, 0, stream>>>(bufB, scale, shift, bufA, n);

  // layer 2: conv + skip
  k_gemm<<<512, 256, 0, stream>>>(bufA, W2, bufB, n);
  k_gather<true><<<gb, 256, 0, stream>>>(bufB, bufA, b2, dis, rowptr, csr_src, out, n);
}

// Round 5
// 429.249 us; speedup vs baseline: 6.9056x; 1.2295x over previous
//
#include <hip/hip_runtime.h>

#define D 128
typedef long long i64;

__device__ inline float4 fma4(float a, float4 b, float4 c) {
  c.x = fmaf(a, b.x, c.x);
  c.y = fmaf(a, b.y, c.y);
  c.z = fmaf(a, b.z, c.z);
  c.w = fmaf(a, b.w, c.w);
  return c;
}

__device__ inline float4 bnrelu4(float4 v, float4 sc, float4 sh) {
  v.x = fmaxf(fmaf(v.x, sc.x, sh.x), 0.f);
  v.y = fmaxf(fmaf(v.y, sc.y, sh.y), 0.f);
  v.z = fmaxf(fmaf(v.z, sc.z, sh.z), 0.f);
  v.w = fmaxf(fmaf(v.w, sc.w, sh.w), 0.f);
  return v;
}

// Detect whether edge_index is int64 (odd u32 words all zero) or int32.
__global__ void k_detect(const unsigned* __restrict__ w, int* __restrict__ flag) {
  __shared__ unsigned red[256];
  unsigned v = 0;
  for (int i = threadIdx.x; i < 2048; i += 256) v |= w[2 * i + 1];
  red[threadIdx.x] = v;
  __syncthreads();
  for (int s = 128; s > 0; s >>= 1) {
    if ((int)threadIdx.x < s) red[threadIdx.x] |= red[threadIdx.x + s];
    __syncthreads();
  }
  if (threadIdx.x == 0) *flag = (red[0] == 0u) ? 1 : 0;
}

// Zero cnt + BN accumulators.
__global__ void k_init(int* __restrict__ cnt, float* __restrict__ colsum,
                       float* __restrict__ colsumsq, int n) {
  int i = blockIdx.x * blockDim.x + threadIdx.x;
  if (i < n) cnt[i] = 0;
  if (i < D) { colsum[i] = 0.f; colsumsq[i] = 0.f; }
}

// Count incoming edges per dst (int atomics).
__global__ void k_count(const int* __restrict__ ei32, const i64* __restrict__ ei64,
                        const int* __restrict__ flag, int e, int* __restrict__ cnt) {
  int is64 = *flag;
  for (long long i = (long long)blockIdx.x * blockDim.x + threadIdx.x; i < e;
       i += (long long)gridDim.x * blockDim.x) {
    int d = is64 ? (int)ei64[e + i] : ei32[e + i];
    atomicAdd(&cnt[d], 1);
  }
}

// Parallel scan, pass 1: per-1024-block sums; also dis = rsqrt(cnt+1).
__global__ __launch_bounds__(1024) void k_scan1(const int* __restrict__ cnt,
                                                int* __restrict__ blocksum,
                                                float* __restrict__ dis, int n) {
  __shared__ int red[1024];
  int t = threadIdx.x;
  int i = blockIdx.x * 1024 + t;
  int c = (i < n) ? cnt[i] : 0;
  if (i < n) dis[i] = rsqrtf((float)(c + 1));
  red[t] = c;
  __syncthreads();
  for (int s = 512; s > 0; s >>= 1) {
    if (t < s) red[t] += red[t + s];
    __syncthreads();
  }
  if (t == 0) blocksum[blockIdx.x] = red[0];
}

// pass 2: exclusive scan of blocksums (nb <= 1024), single block.
__global__ __launch_bounds__(1024) void k_scan2(int* __restrict__ blocksum, int nb) {
  __shared__ int s[1024];
  int t = threadIdx.x;
  int v0 = (t < nb) ? blocksum[t] : 0;
  s[t] = v0;
  __syncthreads();
  for (int off = 1; off < 1024; off <<= 1) {
    int v = (t >= off) ? s[t - off] : 0;
    __syncthreads();
    s[t] += v;
    __syncthreads();
  }
  if (t < nb) blocksum[t] = s[t] - v0;  // exclusive
}

// pass 3: block-local exclusive scan + block offset -> rowptr (row starts).
__global__ __launch_bounds__(1024) void k_scan3(const int* __restrict__ cnt,
                                                const int* __restrict__ blocksum,
                                                int* __restrict__ rowptr, int n) {
  __shared__ int sdata[1024];
  int t = threadIdx.x;
  int i = blockIdx.x * 1024 + t;
  int c = (i < n) ? cnt[i] : 0;
  sdata[t] = c;
  __syncthreads();
  for (int off = 1; off < 1024; off <<= 1) {
    int v = (t >= off) ? sdata[t - off] : 0;
    __syncthreads();
    sdata[t] += v;
    __syncthreads();
  }
  if (i < n) rowptr[i] = blocksum[blockIdx.x] + sdata[t] - c;
}

// Counting-sort fill: slot = rowptr[dst]++ (atomic). Afterwards rowptr[r] == row end.
__global__ void k_fill(const int* __restrict__ ei32, const i64* __restrict__ ei64,
                       const int* __restrict__ flag, int e,
                       int* __restrict__ rowptr, int* __restrict__ csr_src) {
  int is64 = *flag;
  for (long long i = (long long)blockIdx.x * blockDim.x + threadIdx.x; i < e;
       i += (long long)gridDim.x * blockDim.x) {
    int s, d;
    if (is64) { s = (int)ei64[i]; d = (int)ei64[e + i]; }
    else      { s = ei32[i];      d = ei32[e + i]; }
    int slot = atomicAdd(&rowptr[d], 1);
    csr_src[slot] = s;
  }
}

// Y[n x 128] = X[n x 128] @ W[128 x 128], f32 vector ALU (no fp32 MFMA on CDNA4).
// 32-row X tile, 4 rows x 4 cols per thread. BN: apply relu(x*scale+shift) on load.
template <bool BN>
__global__ __launch_bounds__(256) void k_gemm(const float* __restrict__ X,
                                              const float* __restrict__ W,
                                              float* __restrict__ Y, int n,
                                              const float* __restrict__ scale,
                                              const float* __restrict__ shift) {
  __shared__ float Wl[128 * 128];   // 64 KB
  __shared__ float Xl[32][128];     // 16 KB
  int t = threadIdx.x;
  for (int i = t; i < 128 * 32; i += 256)
    ((float4*)Wl)[i] = ((const float4*)W)[i];
  int r0 = t >> 5;            // 0..7
  int c4 = (t & 31) << 2;     // column base
  for (int row0 = blockIdx.x * 32; row0 < n; row0 += gridDim.x * 32) {
    __syncthreads();          // protects W (first iter) and Xl reuse
    int nrows = min(32, n - row0);
    for (int i = t; i < nrows * 32; i += 256) {
      float4 v = ((const float4*)(X + (size_t)row0 * D))[i];
      if (BN) {
        int c = i & 31;
        v = bnrelu4(v, ((const float4*)scale)[c], ((const float4*)shift)[c]);
      }
      ((float4*)Xl)[i] = v;
    }
    __syncthreads();
    float4 a0 = {0.f, 0.f, 0.f, 0.f};
    float4 a1 = {0.f, 0.f, 0.f, 0.f};
    float4 a2 = {0.f, 0.f, 0.f, 0.f};
    float4 a3 = {0.f, 0.f, 0.f, 0.f};
#pragma unroll 8
    for (int k = 0; k < 128; ++k) {
      float4 wv = *(const float4*)&Wl[k * 128 + c4];
      a0 = fma4(Xl[r0][k], wv, a0);
      a1 = fma4(Xl[r0 + 8][k], wv, a1);
      a2 = fma4(Xl[r0 + 16][k], wv, a2);
      a3 = fma4(Xl[r0 + 24][k], wv, a3);
    }
    if (row0 + r0 < n)      *(float4*)&Y[(size_t)(row0 + r0) * D + c4] = a0;
    if (row0 + r0 + 8 < n)  *(float4*)&Y[(size_t)(row0 + r0 + 8) * D + c4] = a1;
    if (row0 + r0 + 16 < n) *(float4*)&Y[(size_t)(row0 + r0 + 16) * D + c4] = a2;
    if (row0 + r0 + 24 < n) *(float4*)&Y[(size_t)(row0 + r0 + 24) * D + c4] = a3;
  }
}

// Pull-gather: one 32-lane group per dst row, 4-way unrolled edge loop.
// out[r] = bias + dis[r]^2*feat[r] (+ skip) + sum_j dis[s_j]*dis[r]*feat[s_j]
// ADD: skip term = relu(addf[r]*scale+shift) (BN fused).
template <bool ADD>
__global__ __launch_bounds__(256) void k_gather(const float* __restrict__ feat,
                                                const float* __restrict__ addf,
                                                const float* __restrict__ bias,
                                                const float* __restrict__ dis,
                                                const int* __restrict__ rowptr,
                                                const int* __restrict__ csr_src,
                                                float* __restrict__ out, int n,
                                                const float* __restrict__ scale,
                                                const float* __restrict__ shift) {
  int r = (blockIdx.x * blockDim.x + threadIdx.x) >> 5;
  if (r >= n) return;
  int lane = threadIdx.x & 31;
  int start = (r == 0) ? 0 : rowptr[r - 1];  // rowptr holds row ENDS after k_fill
  int end = rowptr[r];
  float dr = dis[r];
  float4 acc = ((const float4*)bias)[lane];
  float4 sv = ((const float4*)(feat + (size_t)r * D))[lane];
  acc = fma4(dr * dr, sv, acc);
  if (ADD) {
    float4 h = ((const float4*)(addf + (size_t)r * D))[lane];
    h = bnrelu4(h, ((const float4*)scale)[lane], ((const float4*)shift)[lane]);
    acc.x += h.x; acc.y += h.y; acc.z += h.z; acc.w += h.w;
  }
  float4 acc1 = {0.f, 0.f, 0.f, 0.f};
  int j = start;
  for (; j + 4 <= end; j += 4) {
    int s0 = csr_src[j];
    int s1 = csr_src[j + 1];
    int s2 = csr_src[j + 2];
    int s3 = csr_src[j + 3];
    float w0 = dis[s0] * dr;
    float w1 = dis[s1] * dr;
    float w2 = dis[s2] * dr;
    float w3 = dis[s3] * dr;
    float4 v0 = ((const float4*)(feat + (size_t)s0 * D))[lane];
    float4 v1 = ((const float4*)(feat + (size_t)s1 * D))[lane];
    float4 v2 = ((const float4*)(feat + (size_t)s2 * D))[lane];
    float4 v3 = ((const float4*)(feat + (size_t)s3 * D))[lane];
    acc = fma4(w0, v0, acc);
    acc1 = fma4(w1, v1, acc1);
    acc = fma4(w2, v2, acc);
    acc1 = fma4(w3, v3, acc1);
  }
  for (; j < end; ++j) {
    int s0 = csr_src[j];
    float w0 = dis[s0] * dr;
    float4 v0 = ((const float4*)(feat + (size_t)s0 * D))[lane];
    acc = fma4(w0, v0, acc);
  }
  acc.x += acc1.x; acc.y += acc1.y; acc.z += acc1.z; acc.w += acc1.w;
  ((float4*)(out + (size_t)r * D))[lane] = acc;
}

// Column sums / sum-of-squares for BN (biased var).
__global__ __launch_bounds__(256) void k_bnstats(const float* __restrict__ h, int n,
                                                 float* colsum, float* colsumsq) {
  int t = threadIdx.x;
  int col = t & 127;
  int rh = t >> 7;
  float s = 0.f, s2 = 0.f;
  for (int r = blockIdx.x * 2 + rh; r < n; r += gridDim.x * 2) {
    float v = h[(size_t)r * D + col];
    s += v;
    s2 += v * v;
  }
  atomicAdd(&colsum[col], s);
  atomicAdd(&colsumsq[col], s2);
}

__global__ void k_bnfinish(const float* __restrict__ colsum, const float* __restrict__ colsumsq,
                           const float* __restrict__ gamma, const float* __restrict__ beta,
                           float* __restrict__ scale, float* __restrict__ shift, int n) {
  int d = threadIdx.x;
  float inv_n = 1.0f / (float)n;
  float mu = colsum[d] * inv_n;
  float var = colsumsq[d] * inv_n - mu * mu;
  float sc = gamma[d] * rsqrtf(var + 1e-5f);
  scale[d] = sc;
  shift[d] = beta[d] - mu * sc;
}

extern "C" void kernel_launch(void* const* d_in, const int* in_sizes, int n_in,
                              void* d_out, int out_size, void* d_ws, size_t ws_size,
                              hipStream_t stream) {
  const float* x     = (const float*)d_in[0];
  const int*   ei32  = (const int*)d_in[1];
  const i64*   ei64  = (const i64*)d_in[1];
  const float* W1    = (const float*)d_in[2];
  const float* b1    = (const float*)d_in[3];
  const float* W2    = (const float*)d_in[4];
  const float* b2    = (const float*)d_in[5];
  const float* gamma = (const float*)d_in[6];
  const float* beta  = (const float*)d_in[7];
  float* out = (float*)d_out;

  const int n = in_sizes[0] / D;  // 50000
  const int e = in_sizes[1] / 2;  // 800000

  // Workspace layout (~55 MB):
  size_t npad = ((size_t)n + 255) & ~255ULL;
  size_t epad = ((size_t)e + 255) & ~255ULL;
  float* dis     = (float*)d_ws;            // n
  int*   cnt     = (int*)(dis + npad);      // n
  int*   rowptr  = cnt + npad;              // n (starts -> ends after fill)
  int*   csr_src = rowptr + npad;           // e
  float* bufA    = (float*)(csr_src + epad);// n*D: hw1, then hw2
  float* bufB    = bufA + (size_t)n * D;    // n*D: h1_pre
  float* colsum   = bufB + (size_t)n * D;   // D
  float* colsumsq = colsum + D;             // D
  float* scale    = colsumsq + D;           // D
  float* shift    = scale + D;              // D
  int*   flag     = (int*)(shift + D);      // 1
  int*   blocksum = flag + 256;             // ceil(n/1024)

  int nb256 = (n + 255) / 256;
  int eb256 = (e + 255) / 256;
  int nb1024 = (n + 1023) / 1024;
  int gb    = (n + 7) / 8;  // gather: 8 rows (32-lane groups) per 256-thread block

  // CSR build (shared by both layers)
  k_detect<<<1, 256, 0, stream>>>((const unsigned*)d_in[1], flag);
  k_init<<<nb256, 256, 0, stream>>>(cnt, colsum, colsumsq, n);
  k_count<<<eb256, 256, 0, stream>>>(ei32, ei64, flag, e, cnt);
  k_scan1<<<nb1024, 1024, 0, stream>>>(cnt, blocksum, dis, n);
  k_scan2<<<1, 1024, 0, stream>>>(blocksum, nb1024);
  k_scan3<<<nb1024, 1024, 0, stream>>>(cnt, blocksum, rowptr, n);
  k_fill<<<eb256, 256, 0, stream>>>(ei32, ei64, flag, e, rowptr, csr_src);

  // layer 1: conv -> BN stats
  k_gemm<false><<<512, 256, 0, stream>>>(x, W1, bufA, n, nullptr, nullptr);
  k_gather<false><<<gb, 256, 0, stream>>>(bufA, nullptr, b1, dis, rowptr, csr_src,
                                          bufB, n, nullptr, nullptr);
  k_bnstats<<<1024, 256, 0, stream>>>(bufB, n, colsum, colsumsq);
  k_bnfinish<<<1, D, 0, stream>>>(colsum, colsumsq, gamma, beta, scale, shift, n);

  // layer 2: conv (BN+relu fused into X load) + skip (BN+relu fused into addf)
  k_gemm<true><<<512, 256, 0, stream>>>(bufB, W2, bufA, n, scale, shift);
  k_gather<true><<<gb, 256, 0, stream>>>(bufA, bufB, b2, dis, rowptr, csr_src,
                                         out, n, scale, shift);
}

// Round 6
// 351.692 us; speedup vs baseline: 8.4284x; 1.2205x over previous
//
#include <hip/hip_runtime.h>

#define D 128
typedef long long i64;
typedef unsigned short u16;
typedef unsigned int u32;
typedef __attribute__((ext_vector_type(8))) short bf16x8;
typedef __attribute__((ext_vector_type(4))) float f32x4;

__device__ inline float4 fma4(float a, float4 b, float4 c) {
  c.x = fmaf(a, b.x, c.x);
  c.y = fmaf(a, b.y, c.y);
  c.z = fmaf(a, b.z, c.z);
  c.w = fmaf(a, b.w, c.w);
  return c;
}

__device__ inline float4 bnrelu4(float4 v, float4 sc, float4 sh) {
  v.x = fmaxf(fmaf(v.x, sc.x, sh.x), 0.f);
  v.y = fmaxf(fmaf(v.y, sc.y, sh.y), 0.f);
  v.z = fmaxf(fmaf(v.z, sc.z, sh.z), 0.f);
  v.w = fmaxf(fmaf(v.w, sc.w, sh.w), 0.f);
  return v;
}

__device__ inline u16 f2bf(float f) {  // RNE f32->bf16
  union { float f; u32 u; } v; v.f = f;
  u32 r = (v.u + 0x7FFFu + ((v.u >> 16) & 1u)) >> 16;
  return (u16)r;
}

// unpack 4 bf16 (lane's 8B slice of a 256B row) to float4
__device__ inline float4 ldbf4(const u16* __restrict__ feat, size_t row, int lane) {
  uint2 p = *(const uint2*)(feat + row * D + lane * 4);
  float4 v;
  v.x = __uint_as_float(p.x << 16);
  v.y = __uint_as_float(p.x & 0xFFFF0000u);
  v.z = __uint_as_float(p.y << 16);
  v.w = __uint_as_float(p.y & 0xFFFF0000u);
  return v;
}

// Detect whether edge_index is int64 (odd u32 words all zero) or int32.
__global__ void k_detect(const unsigned* __restrict__ w, int* __restrict__ flag) {
  __shared__ unsigned red[256];
  unsigned v = 0;
  for (int i = threadIdx.x; i < 2048; i += 256) v |= w[2 * i + 1];
  red[threadIdx.x] = v;
  __syncthreads();
  for (int s = 128; s > 0; s >>= 1) {
    if ((int)threadIdx.x < s) red[threadIdx.x] |= red[threadIdx.x + s];
    __syncthreads();
  }
  if (threadIdx.x == 0) *flag = (red[0] == 0u) ? 1 : 0;
}

__global__ void k_init(int* __restrict__ cnt, float* __restrict__ colsum,
                       float* __restrict__ colsumsq, int n) {
  int i = blockIdx.x * blockDim.x + threadIdx.x;
  if (i < n) cnt[i] = 0;
  if (i < D) { colsum[i] = 0.f; colsumsq[i] = 0.f; }
}

__global__ void k_count(const int* __restrict__ ei32, const i64* __restrict__ ei64,
                        const int* __restrict__ flag, int e, int* __restrict__ cnt) {
  int is64 = *flag;
  for (long long i = (long long)blockIdx.x * blockDim.x + threadIdx.x; i < e;
       i += (long long)gridDim.x * blockDim.x) {
    int d = is64 ? (int)ei64[e + i] : ei32[e + i];
    atomicAdd(&cnt[d], 1);
  }
}

// Parallel scan, pass 1: per-1024-block sums; also dis = rsqrt(cnt+1).
__global__ __launch_bounds__(1024) void k_scan1(const int* __restrict__ cnt,
                                                int* __restrict__ blocksum,
                                                float* __restrict__ dis, int n) {
  __shared__ int red[1024];
  int t = threadIdx.x;
  int i = blockIdx.x * 1024 + t;
  int c = (i < n) ? cnt[i] : 0;
  if (i < n) dis[i] = rsqrtf((float)(c + 1));
  red[t] = c;
  __syncthreads();
  for (int s = 512; s > 0; s >>= 1) {
    if (t < s) red[t] += red[t + s];
    __syncthreads();
  }
  if (t == 0) blocksum[blockIdx.x] = red[0];
}

__global__ __launch_bounds__(1024) void k_scan2(int* __restrict__ blocksum, int nb) {
  __shared__ int s[1024];
  int t = threadIdx.x;
  int v0 = (t < nb) ? blocksum[t] : 0;
  s[t] = v0;
  __syncthreads();
  for (int off = 1; off < 1024; off <<= 1) {
    int v = (t >= off) ? s[t - off] : 0;
    __syncthreads();
    s[t] += v;
    __syncthreads();
  }
  if (t < nb) blocksum[t] = s[t] - v0;  // exclusive
}

__global__ __launch_bounds__(1024) void k_scan3(const int* __restrict__ cnt,
                                                const int* __restrict__ blocksum,
                                                int* __restrict__ rowptr, int n) {
  __shared__ int sdata[1024];
  int t = threadIdx.x;
  int i = blockIdx.x * 1024 + t;
  int c = (i < n) ? cnt[i] : 0;
  sdata[t] = c;
  __syncthreads();
  for (int off = 1; off < 1024; off <<= 1) {
    int v = (t >= off) ? sdata[t - off] : 0;
    __syncthreads();
    sdata[t] += v;
    __syncthreads();
  }
  if (i < n) rowptr[i] = blocksum[blockIdx.x] + sdata[t] - c;
}

// Counting-sort fill into u16 src list (n < 65536). rowptr becomes row ENDS.
__global__ void k_fill(const int* __restrict__ ei32, const i64* __restrict__ ei64,
                       const int* __restrict__ flag, int e,
                       int* __restrict__ rowptr, u16* __restrict__ csr_src) {
  int is64 = *flag;
  for (long long i = (long long)blockIdx.x * blockDim.x + threadIdx.x; i < e;
       i += (long long)gridDim.x * blockDim.x) {
    int s, d;
    if (is64) { s = (int)ei64[i]; d = (int)ei64[e + i]; }
    else      { s = ei32[i];      d = ei32[e + i]; }
    int slot = atomicAdd(&rowptr[d], 1);
    csr_src[slot] = (u16)s;
  }
}

// Ybf[n x 128](bf16) = X[n x 128](f32->bf16) @ W[128 x 128](f32->bf16), MFMA.
// Block tile 128x128, 4 waves, each wave 32 rows. BN: relu(x*scale+shift) on load.
// Layouts per m89-verified example: A row=l&15, k=8*(l>>4)+j contiguous;
// B col=l&15, same k slots; D col=lane&15, row=4*(lane>>4)+reg.
#define GR 128
#define LDK 136  // padded leading dim in bf16 elems: 272B rows, 16B-aligned, 2-way banks
template <bool BN>
__global__ __launch_bounds__(256) void k_gemm(const float* __restrict__ X,
                                              const float* __restrict__ W,
                                              u16* __restrict__ Ybf, int n,
                                              const float* __restrict__ scale,
                                              const float* __restrict__ shift) {
  __shared__ u16 Xl[GR * LDK];   // [row][k] ~34 KB
  __shared__ u16 Wt[128 * LDK];  // [col][k] ~34 KB
  int t = threadIdx.x;
  int row0 = blockIdx.x * GR;
  {  // stage Wt transposed (bf16)
    int kk = t >> 5;
    int c4 = (t & 31) << 2;
    for (int k = kk; k < 128; k += 8) {
      float4 w = *(const float4*)&W[k * D + c4];
      Wt[(c4 + 0) * LDK + k] = f2bf(w.x);
      Wt[(c4 + 1) * LDK + k] = f2bf(w.y);
      Wt[(c4 + 2) * LDK + k] = f2bf(w.z);
      Wt[(c4 + 3) * LDK + k] = f2bf(w.w);
    }
  }
  {  // stage Xl (bf16), optional BN+relu
    int r = t >> 5;
    int c4 = (t & 31) << 2;
    float4 sc, sh;
    if (BN) { sc = ((const float4*)scale)[t & 31]; sh = ((const float4*)shift)[t & 31]; }
    for (int rr = r; rr < GR; rr += 8) {
      int gr = row0 + rr;
      float4 v = {0.f, 0.f, 0.f, 0.f};
      if (gr < n) v = *(const float4*)&X[(size_t)gr * D + c4];
      if (BN) v = bnrelu4(v, sc, sh);
      uint2 pk;
      pk.x = (u32)f2bf(v.x) | ((u32)f2bf(v.y) << 16);
      pk.y = (u32)f2bf(v.z) | ((u32)f2bf(v.w) << 16);
      *(uint2*)&Xl[rr * LDK + c4] = pk;
    }
  }
  __syncthreads();
  int wv = t >> 6;       // wave 0..3
  int l = t & 63;
  int lg = l >> 4;       // 0..3
  int li = l & 15;
  int wr = wv * 32;      // wave's row base in tile
  f32x4 acc[2][8];
#pragma unroll
  for (int m = 0; m < 2; ++m)
#pragma unroll
    for (int nf = 0; nf < 8; ++nf)
      acc[m][nf] = (f32x4){0.f, 0.f, 0.f, 0.f};
#pragma unroll
  for (int ks = 0; ks < 4; ++ks) {
    int k0 = ks * 32 + lg * 8;
    bf16x8 a0 = *(const bf16x8*)&Xl[(wr + li) * LDK + k0];
    bf16x8 a1 = *(const bf16x8*)&Xl[(wr + 16 + li) * LDK + k0];
#pragma unroll
    for (int nf = 0; nf < 8; ++nf) {
      bf16x8 b = *(const bf16x8*)&Wt[(nf * 16 + li) * LDK + k0];
      acc[0][nf] = __builtin_amdgcn_mfma_f32_16x16x32_bf16(a0, b, acc[0][nf], 0, 0, 0);
      acc[1][nf] = __builtin_amdgcn_mfma_f32_16x16x32_bf16(a1, b, acc[1][nf], 0, 0, 0);
    }
  }
  // write D as bf16: frag (m,nf): row = row0+wr+16m+4*lg+r, col = 16*nf+li
#pragma unroll
  for (int m = 0; m < 2; ++m) {
#pragma unroll
    for (int r = 0; r < 4; ++r) {
      int grow = row0 + wr + 16 * m + lg * 4 + r;
      if (grow < n) {
        u16* orow = Ybf + (size_t)grow * D;
#pragma unroll
        for (int nf = 0; nf < 8; ++nf)
          orow[nf * 16 + li] = f2bf(acc[m][nf][r]);
      }
    }
  }
}

// Pull-gather from bf16 features: one 32-lane group per dst row.
// out(f32)[r] = bias + dis[r]^2*feat[r] (+ skip) + sum_j dis[s_j]*dis[r]*feat[s_j]
// ADD: skip = relu(addf[r]*scale+shift) with addf f32 (BN fused).
template <bool ADD>
__global__ __launch_bounds__(256) void k_gather(const u16* __restrict__ feat,
                                                const float* __restrict__ addf,
                                                const float* __restrict__ bias,
                                                const float* __restrict__ dis,
                                                const int* __restrict__ rowptr,
                                                const u16* __restrict__ csr_src,
                                                float* __restrict__ out, int n,
                                                const float* __restrict__ scale,
                                                const float* __restrict__ shift) {
  int r = (blockIdx.x * blockDim.x + threadIdx.x) >> 5;
  if (r >= n) return;
  int lane = threadIdx.x & 31;
  int start = (r == 0) ? 0 : rowptr[r - 1];  // rowptr holds row ENDS after k_fill
  int end = rowptr[r];
  float dr = dis[r];
  float4 acc = ((const float4*)bias)[lane];
  float4 sv = ldbf4(feat, (size_t)r, lane);
  acc = fma4(dr * dr, sv, acc);
  if (ADD) {
    float4 h = ((const float4*)(addf + (size_t)r * D))[lane];
    h = bnrelu4(h, ((const float4*)scale)[lane], ((const float4*)shift)[lane]);
    acc.x += h.x; acc.y += h.y; acc.z += h.z; acc.w += h.w;
  }
  float4 acc1 = {0.f, 0.f, 0.f, 0.f};
  int j = start;
  for (; j + 4 <= end; j += 4) {
    int s0 = csr_src[j];
    int s1 = csr_src[j + 1];
    int s2 = csr_src[j + 2];
    int s3 = csr_src[j + 3];
    float w0 = dis[s0] * dr;
    float w1 = dis[s1] * dr;
    float w2 = dis[s2] * dr;
    float w3 = dis[s3] * dr;
    float4 v0 = ldbf4(feat, (size_t)s0, lane);
    float4 v1 = ldbf4(feat, (size_t)s1, lane);
    float4 v2 = ldbf4(feat, (size_t)s2, lane);
    float4 v3 = ldbf4(feat, (size_t)s3, lane);
    acc = fma4(w0, v0, acc);
    acc1 = fma4(w1, v1, acc1);
    acc = fma4(w2, v2, acc);
    acc1 = fma4(w3, v3, acc1);
  }
  for (; j < end; ++j) {
    int s0 = csr_src[j];
    float w0 = dis[s0] * dr;
    float4 v0 = ldbf4(feat, (size_t)s0, lane);
    acc = fma4(w0, v0, acc);
  }
  acc.x += acc1.x; acc.y += acc1.y; acc.z += acc1.z; acc.w += acc1.w;
  ((float4*)(out + (size_t)r * D))[lane] = acc;
}

// Column sums / sum-of-squares for BN (biased var), f32 input.
__global__ __launch_bounds__(256) void k_bnstats(const float* __restrict__ h, int n,
                                                 float* colsum, float* colsumsq) {
  int t = threadIdx.x;
  int col = t & 127;
  int rh = t >> 7;
  float s = 0.f, s2 = 0.f;
  for (int r = blockIdx.x * 2 + rh; r < n; r += gridDim.x * 2) {
    float v = h[(size_t)r * D + col];
    s += v;
    s2 += v * v;
  }
  atomicAdd(&colsum[col], s);
  atomicAdd(&colsumsq[col], s2);
}

__global__ void k_bnfinish(const float* __restrict__ colsum, const float* __restrict__ colsumsq,
                           const float* __restrict__ gamma, const float* __restrict__ beta,
                           float* __restrict__ scale, float* __restrict__ shift, int n) {
  int d = threadIdx.x;
  float inv_n = 1.0f / (float)n;
  float mu = colsum[d] * inv_n;
  float var = colsumsq[d] * inv_n - mu * mu;
  float sc = gamma[d] * rsqrtf(var + 1e-5f);
  scale[d] = sc;
  shift[d] = beta[d] - mu * sc;
}

extern "C" void kernel_launch(void* const* d_in, const int* in_sizes, int n_in,
                              void* d_out, int out_size, void* d_ws, size_t ws_size,
                              hipStream_t stream) {
  const float* x     = (const float*)d_in[0];
  const int*   ei32  = (const int*)d_in[1];
  const i64*   ei64  = (const i64*)d_in[1];
  const float* W1    = (const float*)d_in[2];
  const float* b1    = (const float*)d_in[3];
  const float* W2    = (const float*)d_in[4];
  const float* b2    = (const float*)d_in[5];
  const float* gamma = (const float*)d_in[6];
  const float* beta  = (const float*)d_in[7];
  float* out = (float*)d_out;

  const int n = in_sizes[0] / D;  // 50000
  const int e = in_sizes[1] / 2;  // 800000

  // Workspace layout (~41 MB)
  size_t npad = ((size_t)n + 255) & ~255ULL;
  size_t epad = ((size_t)e + 255) & ~255ULL;
  char* p = (char*)d_ws;
  float* dis    = (float*)p; p += npad * 4;
  int*   cnt    = (int*)p;   p += npad * 4;
  int*   rowptr = (int*)p;   p += npad * 4;
  u16*   csr16  = (u16*)p;   p += epad * 2;
  u16*   bf_buf = (u16*)p;   p += (size_t)n * D * 2;  // hw1 then hw2 (bf16)
  float* bufB   = (float*)p; p += (size_t)n * D * 4;  // h1pre (f32)
  float* colsum   = (float*)p; p += D * 4;
  float* colsumsq = (float*)p; p += D * 4;
  float* scale    = (float*)p; p += D * 4;
  float* shift    = (float*)p; p += D * 4;
  int*   flag     = (int*)p;   p += 256 * 4;
  int*   blocksum = (int*)p;

  int nb256 = (n + 255) / 256;
  int eb256 = (e + 255) / 256;
  int nb1024 = (n + 1023) / 1024;
  int gb = (n + 7) / 8;          // gather: 8 rows per 256-thread block
  int mb = (n + GR - 1) / GR;    // gemm: 128 rows per block

  // CSR build (shared by both layers)
  k_detect<<<1, 256, 0, stream>>>((const unsigned*)d_in[1], flag);
  k_init<<<nb256, 256, 0, stream>>>(cnt, colsum, colsumsq, n);
  k_count<<<eb256, 256, 0, stream>>>(ei32, ei64, flag, e, cnt);
  k_scan1<<<nb1024, 1024, 0, stream>>>(cnt, blocksum, dis, n);
  k_scan2<<<1, 1024, 0, stream>>>(blocksum, nb1024);
  k_scan3<<<nb1024, 1024, 0, stream>>>(cnt, blocksum, rowptr, n);
  k_fill<<<eb256, 256, 0, stream>>>(ei32, ei64, flag, e, rowptr, csr16);

  // layer 1: conv (MFMA, bf16 out) -> gather -> BN stats
  k_gemm<false><<<mb, 256, 0, stream>>>(x, W1, bf_buf, n, nullptr, nullptr);
  k_gather<false><<<gb, 256, 0, stream>>>(bf_buf, nullptr, b1, dis, rowptr, csr16,
                                          bufB, n, nullptr, nullptr);
  k_bnstats<<<1024, 256, 0, stream>>>(bufB, n, colsum, colsumsq);
  k_bnfinish<<<1, D, 0, stream>>>(colsum, colsumsq, gamma, beta, scale, shift, n);

  // layer 2: conv (BN+relu fused into staging) + gather with fused skip
  k_gemm<true><<<mb, 256, 0, stream>>>(bufB, W2, bf_buf, n, scale, shift);
  k_gather<true><<<gb, 256, 0, stream>>>(bf_buf, bufB, b2, dis, rowptr, csr16,
                                         out, n, scale, shift);
}

// Round 8
// 309.302 us; speedup vs baseline: 9.5835x; 1.1371x over previous
//
#include <hip/hip_runtime.h>

#define D 128
typedef long long i64;
typedef unsigned short u16;
typedef unsigned int u32;
typedef __attribute__((ext_vector_type(8))) short bf16x8;
typedef __attribute__((ext_vector_type(4))) float f32x4;

__device__ inline float4 fma4(float a, float4 b, float4 c) {
  c.x = fmaf(a, b.x, c.x);
  c.y = fmaf(a, b.y, c.y);
  c.z = fmaf(a, b.z, c.z);
  c.w = fmaf(a, b.w, c.w);
  return c;
}

__device__ inline float4 bnrelu4(float4 v, float4 sc, float4 sh) {
  v.x = fmaxf(fmaf(v.x, sc.x, sh.x), 0.f);
  v.y = fmaxf(fmaf(v.y, sc.y, sh.y), 0.f);
  v.z = fmaxf(fmaf(v.z, sc.z, sh.z), 0.f);
  v.w = fmaxf(fmaf(v.w, sc.w, sh.w), 0.f);
  return v;
}

__device__ inline u16 f2bf(float f) {  // RNE f32->bf16
  union { float f; u32 u; } v; v.f = f;
  u32 r = (v.u + 0x7FFFu + ((v.u >> 16) & 1u)) >> 16;
  return (u16)r;
}

__device__ inline uint2 pk4(float4 v) {
  uint2 p;
  p.x = (u32)f2bf(v.x) | ((u32)f2bf(v.y) << 16);
  p.y = (u32)f2bf(v.z) | ((u32)f2bf(v.w) << 16);
  return p;
}

__device__ inline float4 unpk4(uint2 p) {
  float4 v;
  v.x = __uint_as_float(p.x << 16);
  v.y = __uint_as_float(p.x & 0xFFFF0000u);
  v.z = __uint_as_float(p.y << 16);
  v.w = __uint_as_float(p.y & 0xFFFF0000u);
  return v;
}

// unpack 4 bf16 (lane's 8B slice of a 256B row) to float4
__device__ inline float4 ldbf4(const u16* __restrict__ feat, size_t row, int lane) {
  return unpk4(*(const uint2*)(feat + row * D + lane * 4));
}

// Merged: block 0 detects int64-vs-int32 edge_index; blocks >=1 zero cnt.
__global__ void k_initdet(const unsigned* __restrict__ w, int* __restrict__ flag,
                          int* __restrict__ cnt, int n) {
  if (blockIdx.x == 0) {
    __shared__ unsigned red[256];
    unsigned v = 0;
    for (int i = threadIdx.x; i < 2048; i += 256) v |= w[2 * i + 1];
    red[threadIdx.x] = v;
    __syncthreads();
    for (int s = 128; s > 0; s >>= 1) {
      if ((int)threadIdx.x < s) red[threadIdx.x] |= red[threadIdx.x + s];
      __syncthreads();
    }
    if (threadIdx.x == 0) *flag = (red[0] == 0u) ? 1 : 0;
  } else {
    int i = (blockIdx.x - 1) * blockDim.x + threadIdx.x;
    if (i < n) cnt[i] = 0;
  }
}

__global__ void k_count(const int* __restrict__ ei32, const i64* __restrict__ ei64,
                        const int* __restrict__ flag, int e, int* __restrict__ cnt) {
  int is64 = *flag;
  for (long long i = (long long)blockIdx.x * blockDim.x + threadIdx.x; i < e;
       i += (long long)gridDim.x * blockDim.x) {
    int d = is64 ? (int)ei64[e + i] : ei32[e + i];
    atomicAdd(&cnt[d], 1);
  }
}

// Parallel scan, pass 1: per-1024-block sums; also dis = rsqrt(cnt+1).
__global__ __launch_bounds__(1024) void k_scan1(const int* __restrict__ cnt,
                                                int* __restrict__ blocksum,
                                                float* __restrict__ dis, int n) {
  __shared__ int red[1024];
  int t = threadIdx.x;
  int i = blockIdx.x * 1024 + t;
  int c = (i < n) ? cnt[i] : 0;
  if (i < n) dis[i] = rsqrtf((float)(c + 1));
  red[t] = c;
  __syncthreads();
  for (int s = 512; s > 0; s >>= 1) {
    if (t < s) red[t] += red[t + s];
    __syncthreads();
  }
  if (t == 0) blocksum[blockIdx.x] = red[0];
}

__global__ __launch_bounds__(1024) void k_scan2(int* __restrict__ blocksum, int nb) {
  __shared__ int s[1024];
  int t = threadIdx.x;
  int v0 = (t < nb) ? blocksum[t] : 0;
  s[t] = v0;
  __syncthreads();
  for (int off = 1; off < 1024; off <<= 1) {
    int v = (t >= off) ? s[t - off] : 0;
    __syncthreads();
    s[t] += v;
    __syncthreads();
  }
  if (t < nb) blocksum[t] = s[t] - v0;  // exclusive
}

__global__ __launch_bounds__(1024) void k_scan3(const int* __restrict__ cnt,
                                                const int* __restrict__ blocksum,
                                                int* __restrict__ rowptr, int n) {
  __shared__ int sdata[1024];
  int t = threadIdx.x;
  int i = blockIdx.x * 1024 + t;
  int c = (i < n) ? cnt[i] : 0;
  sdata[t] = c;
  __syncthreads();
  for (int off = 1; off < 1024; off <<= 1) {
    int v = (t >= off) ? sdata[t - off] : 0;
    __syncthreads();
    sdata[t] += v;
    __syncthreads();
  }
  if (i < n) rowptr[i] = blocksum[blockIdx.x] + sdata[t] - c;
}

// Counting-sort fill into u16 src list (n < 65536). rowptr becomes row ENDS.
__global__ void k_fill(const int* __restrict__ ei32, const i64* __restrict__ ei64,
                       const int* __restrict__ flag, int e,
                       int* __restrict__ rowptr, u16* __restrict__ csr_src) {
  int is64 = *flag;
  for (long long i = (long long)blockIdx.x * blockDim.x + threadIdx.x; i < e;
       i += (long long)gridDim.x * blockDim.x) {
    int s, d;
    if (is64) { s = (int)ei64[i]; d = (int)ei64[e + i]; }
    else      { s = ei32[i];      d = ei32[e + i]; }
    int slot = atomicAdd(&rowptr[d], 1);
    csr_src[slot] = (u16)s;
  }
}

// Ybf[n x 128](bf16) = X @ W, MFMA bf16, f32 accum. X f32 (XBF=0) or bf16 (XBF=1).
// Block tile 128x128, 4 waves x 32 rows. BN: relu(x*scale+shift) fused on load.
// Layouts (m89-verified): A row=l&15, k=8*(l>>4)+j; B col=l&15 same k;
// D col=lane&15, row=4*(lane>>4)+reg.
#define GR 128
#define LDK 136  // padded bf16 leading dim: 272B rows, 16B-aligned, 2-way banks (free)
template <bool BN, bool XBF>
__global__ __launch_bounds__(256) void k_gemm(const float* __restrict__ Xf,
                                              const u16* __restrict__ Xb,
                                              const float* __restrict__ W,
                                              u16* __restrict__ Ybf, int n,
                                              const float* __restrict__ scale,
                                              const float* __restrict__ shift) {
  __shared__ u16 Xl[GR * LDK];   // ~34 KB
  __shared__ u16 Wt[128 * LDK];  // ~34 KB
  int t = threadIdx.x;
  int row0 = blockIdx.x * GR;
  {  // stage Wt transposed (bf16)
    int kk = t >> 5;
    int c4 = (t & 31) << 2;
    for (int k = kk; k < 128; k += 8) {
      float4 w = *(const float4*)&W[k * D + c4];
      Wt[(c4 + 0) * LDK + k] = f2bf(w.x);
      Wt[(c4 + 1) * LDK + k] = f2bf(w.y);
      Wt[(c4 + 2) * LDK + k] = f2bf(w.z);
      Wt[(c4 + 3) * LDK + k] = f2bf(w.w);
    }
  }
  {  // stage Xl (bf16), optional BN+relu
    int r = t >> 5;
    int c4 = (t & 31) << 2;
    float4 sc, sh;
    if (BN) { sc = ((const float4*)scale)[t & 31]; sh = ((const float4*)shift)[t & 31]; }
    for (int rr = r; rr < GR; rr += 8) {
      int gr = row0 + rr;
      uint2 pk = {0u, 0u};
      if (gr < n) {
        if (XBF) {
          pk = *(const uint2*)&Xb[(size_t)gr * D + c4];
          if (BN) pk = pk4(bnrelu4(unpk4(pk), sc, sh));
        } else {
          float4 v = *(const float4*)&Xf[(size_t)gr * D + c4];
          if (BN) v = bnrelu4(v, sc, sh);
          pk = pk4(v);
        }
      }
      *(uint2*)&Xl[rr * LDK + c4] = pk;
    }
  }
  __syncthreads();
  int wv = t >> 6;       // wave 0..3
  int l = t & 63;
  int lg = l >> 4;       // 0..3
  int li = l & 15;
  int wr = wv * 32;      // wave's row base in tile
  f32x4 acc[2][8];
#pragma unroll
  for (int m = 0; m < 2; ++m)
#pragma unroll
    for (int nf = 0; nf < 8; ++nf)
      acc[m][nf] = (f32x4){0.f, 0.f, 0.f, 0.f};
#pragma unroll
  for (int ks = 0; ks < 4; ++ks) {
    int k0 = ks * 32 + lg * 8;
    bf16x8 a0 = *(const bf16x8*)&Xl[(wr + li) * LDK + k0];
    bf16x8 a1 = *(const bf16x8*)&Xl[(wr + 16 + li) * LDK + k0];
#pragma unroll
    for (int nf = 0; nf < 8; ++nf) {
      bf16x8 b = *(const bf16x8*)&Wt[(nf * 16 + li) * LDK + k0];
      acc[0][nf] = __builtin_amdgcn_mfma_f32_16x16x32_bf16(a0, b, acc[0][nf], 0, 0, 0);
      acc[1][nf] = __builtin_amdgcn_mfma_f32_16x16x32_bf16(a1, b, acc[1][nf], 0, 0, 0);
    }
  }
#pragma unroll
  for (int m = 0; m < 2; ++m) {
#pragma unroll
    for (int r = 0; r < 4; ++r) {
      int grow = row0 + wr + 16 * m + lg * 4 + r;
      if (grow < n) {
        u16* orow = Ybf + (size_t)grow * D;
#pragma unroll
        for (int nf = 0; nf < 8; ++nf)
          orow[nf * 16 + li] = f2bf(acc[m][nf][r]);
      }
    }
  }
}

// Pull-gather, one 32-lane group per dst row, grid-stride over rows.
// L2=false (layer1): out bf16 h1pre; accumulate BN col-stats -> block partials.
// L2=true  (layer2): skip = relu(BN(h1bf)) added; out f32 (final).
template <bool L2>
__global__ __launch_bounds__(256) void k_gather(const u16* __restrict__ feat,
                                                const u16* __restrict__ h1bf,
                                                const float* __restrict__ bias,
                                                const float* __restrict__ dis,
                                                const int* __restrict__ rowptr,
                                                const u16* __restrict__ csr_src,
                                                float* __restrict__ outf,
                                                u16* __restrict__ outb, int n,
                                                const float* __restrict__ scale,
                                                const float* __restrict__ shift,
                                                float* __restrict__ partial) {
  __shared__ float s_l[8][128];
  __shared__ float q_l[8][128];
  int t = threadIdx.x;
  int lane = t & 31;
  int g = t >> 5;
  int ngroups = gridDim.x * 8;
  float4 s4 = {0.f, 0.f, 0.f, 0.f};
  float4 q4 = {0.f, 0.f, 0.f, 0.f};
  float4 bv = ((const float4*)bias)[lane];
  float4 sc, sh;
  if (L2) { sc = ((const float4*)scale)[lane]; sh = ((const float4*)shift)[lane]; }
  for (int r = blockIdx.x * 8 + g; r < n; r += ngroups) {
    int start = (r == 0) ? 0 : rowptr[r - 1];  // rowptr holds row ENDS after k_fill
    int end = rowptr[r];
    float dr = dis[r];
    float4 acc = bv;
    float4 sv = ldbf4(feat, (size_t)r, lane);
    acc = fma4(dr * dr, sv, acc);
    if (L2) {
      float4 h = bnrelu4(ldbf4(h1bf, (size_t)r, lane), sc, sh);
      acc.x += h.x; acc.y += h.y; acc.z += h.z; acc.w += h.w;
    }
    float4 acc1 = {0.f, 0.f, 0.f, 0.f};
    int j = start;
    for (; j + 4 <= end; j += 4) {
      int s0 = csr_src[j];
      int s1 = csr_src[j + 1];
      int s2 = csr_src[j + 2];
      int s3 = csr_src[j + 3];
      float w0 = dis[s0] * dr;
      float w1 = dis[s1] * dr;
      float w2 = dis[s2] * dr;
      float w3 = dis[s3] * dr;
      float4 v0 = ldbf4(feat, (size_t)s0, lane);
      float4 v1 = ldbf4(feat, (size_t)s1, lane);
      float4 v2 = ldbf4(feat, (size_t)s2, lane);
      float4 v3 = ldbf4(feat, (size_t)s3, lane);
      acc = fma4(w0, v0, acc);
      acc1 = fma4(w1, v1, acc1);
      acc = fma4(w2, v2, acc);
      acc1 = fma4(w3, v3, acc1);
    }
    for (; j < end; ++j) {
      int s0 = csr_src[j];
      float w0 = dis[s0] * dr;
      acc = fma4(w0, ldbf4(feat, (size_t)s0, lane), acc);
    }
    acc.x += acc1.x; acc.y += acc1.y; acc.z += acc1.z; acc.w += acc1.w;
    if (L2) {
      ((float4*)(outf + (size_t)r * D))[lane] = acc;
    } else {
      *(uint2*)(outb + (size_t)r * D + lane * 4) = pk4(acc);
      s4.x += acc.x; s4.y += acc.y; s4.z += acc.z; s4.w += acc.w;
      q4.x = fmaf(acc.x, acc.x, q4.x);
      q4.y = fmaf(acc.y, acc.y, q4.y);
      q4.z = fmaf(acc.z, acc.z, q4.z);
      q4.w = fmaf(acc.w, acc.w, q4.w);
    }
  }
  if (!L2) {
    *(float4*)&s_l[g][lane * 4] = s4;
    *(float4*)&q_l[g][lane * 4] = q4;
    __syncthreads();
    float v = 0.f;
    if (t < 128) {
#pragma unroll
      for (int gg = 0; gg < 8; ++gg) v += s_l[gg][t];
    } else {
#pragma unroll
      for (int gg = 0; gg < 8; ++gg) v += q_l[gg][t - 128];
    }
    partial[blockIdx.x * 256 + t] = v;  // [0..127]=colsum, [128..255]=colsumsq
  }
}

// Fold block partials -> mu/var -> scale/shift. One block per column.
__global__ __launch_bounds__(256) void k_bnreduce(const float* __restrict__ partial,
                                                  int nbp,
                                                  const float* __restrict__ gamma,
                                                  const float* __restrict__ beta,
                                                  float* __restrict__ scale,
                                                  float* __restrict__ shift, int n) {
  __shared__ float rs[256], rq[256];
  int c = blockIdx.x;  // 0..127
  int t = threadIdx.x;
  float s = 0.f, q = 0.f;
  for (int b = t; b < nbp; b += 256) {
    s += partial[b * 256 + c];
    q += partial[b * 256 + 128 + c];
  }
  rs[t] = s; rq[t] = q;
  __syncthreads();
  for (int st = 128; st > 0; st >>= 1) {
    if (t < st) { rs[t] += rs[t + st]; rq[t] += rq[t + st]; }
    __syncthreads();
  }
  if (t == 0) {
    float inv_n = 1.0f / (float)n;
    float mu = rs[0] * inv_n;
    float var = rq[0] * inv_n - mu * mu;
    float sc = gamma[c] * rsqrtf(var + 1e-5f);
    scale[c] = sc;
    shift[c] = beta[c] - mu * sc;
  }
}

extern "C" void kernel_launch(void* const* d_in, const int* in_sizes, int n_in,
                              void* d_out, int out_size, void* d_ws, size_t ws_size,
                              hipStream_t stream) {
  const float* x     = (const float*)d_in[0];
  const int*   ei32  = (const int*)d_in[1];
  const i64*   ei64  = (const i64*)d_in[1];
  const float* W1    = (const float*)d_in[2];
  const float* b1    = (const float*)d_in[3];
  const float* W2    = (const float*)d_in[4];
  const float* b2    = (const float*)d_in[5];
  const float* gamma = (const float*)d_in[6];
  const float* beta  = (const float*)d_in[7];
  float* out = (float*)d_out;

  const int n = in_sizes[0] / D;  // 50000
  const int e = in_sizes[1] / 2;  // 800000
  const int GB1 = 1024;           // persistent gather1 blocks (stats partials)

  // Workspace layout (~29 MB)
  size_t npad = ((size_t)n + 255) & ~255ULL;
  size_t epad = ((size_t)e + 255) & ~255ULL;
  char* p = (char*)d_ws;
  float* dis    = (float*)p; p += npad * 4;
  int*   cnt    = (int*)p;   p += npad * 4;
  int*   rowptr = (int*)p;   p += npad * 4;
  u16*   csr16  = (u16*)p;   p += epad * 2;
  u16*   hwbf   = (u16*)p;   p += (size_t)n * D * 2;  // gemm out (hw1, then hw2)
  u16*   h1bf   = (u16*)p;   p += (size_t)n * D * 2;  // h1pre (bf16)
  float* partial = (float*)p; p += (size_t)GB1 * 256 * 4;
  float* scale   = (float*)p; p += D * 4;
  float* shift   = (float*)p; p += D * 4;
  int*   flag    = (int*)p;   p += 256 * 4;
  int*   blocksum = (int*)p;

  int nb256 = (n + 255) / 256;
  int eb256 = (e + 255) / 256;
  int nb1024 = (n + 1023) / 1024;
  int gb = (n + 7) / 8;          // gather2: 8 rows per 256-thread block
  int mb = (n + GR - 1) / GR;    // gemm: 128 rows per block

  // CSR build (shared by both layers)
  k_initdet<<<nb256 + 1, 256, 0, stream>>>((const unsigned*)d_in[1], flag, cnt, n);
  k_count<<<eb256, 256, 0, stream>>>(ei32, ei64, flag, e, cnt);
  k_scan1<<<nb1024, 1024, 0, stream>>>(cnt, blocksum, dis, n);
  k_scan2<<<1, 1024, 0, stream>>>(blocksum, nb1024);
  k_scan3<<<nb1024, 1024, 0, stream>>>(cnt, blocksum, rowptr, n);
  k_fill<<<eb256, 256, 0, stream>>>(ei32, ei64, flag, e, rowptr, csr16);

  // layer 1: conv (MFMA) -> gather (+fused BN stats) -> scale/shift
  k_gemm<false, false><<<mb, 256, 0, stream>>>(x, nullptr, W1, hwbf, n, nullptr, nullptr);
  k_gather<false><<<GB1, 256, 0, stream>>>(hwbf, nullptr, b1, dis, rowptr, csr16,
                                           nullptr, h1bf, n, nullptr, nullptr, partial);
  k_bnreduce<<<D, 256, 0, stream>>>(partial, GB1, gamma, beta, scale, shift, n);

  // layer 2: conv (BN+relu fused, bf16 in) + gather with fused BN'd skip
  k_gemm<true, true><<<mb, 256, 0, stream>>>(nullptr, h1bf, W2, hwbf, n, scale, shift);
  k_gather<true><<<gb, 256, 0, stream>>>(hwbf, h1bf, b2, dis, rowptr, csr16,
                                         out, nullptr, n, scale, shift, nullptr);
}